// Round 10
// baseline (506.802 us; speedup 1.0000x reference)
//
#include <hip/hip_runtime.h>
#include <cstddef>
#include <cstdint>

// ---------------------------------------------------------------------------
// JKNet, aggregate-first + fp16 hidden states + MFMA GEMMs.
//   xs = fp16(x*invo);           aggA = A@xs (fp16 out)
//   h1 = relu((aggA@W1)*invi+b1) via MFMA; emits h1s=fp16(h1*invo), h1h=fp16(h1)
//   aggB = A@h1s (fp16 out);     h2h = fp16(relu((aggB@W2)*invi+b2)) via MFMA
//   z = fp16(h1h@Wo1 + h2h@Wo2) via MFMA (K=256 in two 128-halves)
//   out[v] = sum_{e:dst=v} z[src] + bout   (fp16 gather, f32 accum/out)
// R8: MFMA GEMMs (mfma_f32_16x16x32_f16, m89/m91-verified layout); fp16
//     hidden-state tables -> gathers at per-XCD traffic floor (FETCH 175MB
//     ~= 8 XCDs x 25.6MB).
// R9: z table to fp16 (error ~2e-3 through the 16-edge sum; halves z-gather
//     traffic); CHUNKS 32->16 (halves hist-array side traffic in build).
// ---------------------------------------------------------------------------

#define THREADS 256
#define RANGE 25600      // nodes per LDS histogram slice (100 KB LDS)
#define CHUNKS 16        // edge chunks

typedef float f32x4 __attribute__((ext_vector_type(4)));
typedef _Float16 h8 __attribute__((ext_vector_type(8)));

__device__ __forceinline__ void nt_store_f4(const float4 s, float4* dst) {
  f32x4 v; v.x = s.x; v.y = s.y; v.z = s.z; v.w = s.w;
  __builtin_nontemporal_store(v, (f32x4*)dst);
}

// ---- 2D histogram: hist[c][v] = #edges in chunk c with key==v ---------------
__global__ __launch_bounds__(THREADS)
void k_hist(const int* __restrict__ dst, const int* __restrict__ src,
            int* __restrict__ histD, int* __restrict__ histS,
            int N, int E, int ranges) {
  __shared__ int h[RANGE];
  int aid = blockIdx.x & 1;
  int r = (blockIdx.x >> 1) % ranges;
  int c = (blockIdx.x >> 1) / ranges;
  const int* arr = aid ? src : dst;
  int* hist = aid ? histS : histD;
  int lo = r * RANGE;
  unsigned span = (unsigned)min(RANGE, N - lo);
  int t = threadIdx.x;
  for (int j = t; j < RANGE; j += THREADS) h[j] = 0;
  __syncthreads();

  int beg = (int)((long long)c * E / CHUNKS);
  int end = (int)((long long)(c + 1) * E / CHUNKS);
  int a = min(end, (beg + 3) & ~3);
  for (int i = beg + t; i < a; i += THREADS) {
    unsigned u = (unsigned)(arr[i] - lo);
    if (u < span) atomicAdd(&h[u], 1);
  }
  for (int i4 = a + t * 4; i4 + 3 < end; i4 += THREADS * 4) {
    int4 v = *(const int4*)(arr + i4);
    unsigned u0 = (unsigned)(v.x - lo), u1 = (unsigned)(v.y - lo);
    unsigned u2 = (unsigned)(v.z - lo), u3 = (unsigned)(v.w - lo);
    if (u0 < span) atomicAdd(&h[u0], 1);
    if (u1 < span) atomicAdd(&h[u1], 1);
    if (u2 < span) atomicAdd(&h[u2], 1);
    if (u3 < span) atomicAdd(&h[u3], 1);
  }
  int tail = a + ((end - a) & ~3);
  for (int i = tail + t; i < end; i += THREADS) {
    unsigned u = (unsigned)(arr[i] - lo);
    if (u < span) atomicAdd(&h[u], 1);
  }
  __syncthreads();
  for (int j = t; j < (int)span; j += THREADS) hist[(size_t)c * N + lo + j] = h[j];
}

// ---- reduce hist columns -> deg_i, invi, invo ------------------------------
__global__ void k_redinv(const int* __restrict__ histD, const int* __restrict__ histS,
                         int* __restrict__ deg_i, float* __restrict__ inv_in,
                         float* __restrict__ inv_out, int N) {
  int v = blockIdx.x * blockDim.x + threadIdx.x;
  if (v >= N) return;
  int sD = 0, sS = 0;
#pragma unroll
  for (int c = 0; c < CHUNKS; ++c) {
    sD += histD[(size_t)c * N + v];
    sS += histS[(size_t)c * N + v];
  }
  deg_i[v] = sD;
  inv_in[v]  = rsqrtf((float)max(sD, 1));
  inv_out[v] = rsqrtf((float)max(sS, 1));
}

// ---- exclusive scan of deg_i -> row_ptr (3 kernels, chunk=1024) ------------
__global__ void k_scan1(const int* __restrict__ deg, int* __restrict__ incl,
                        int* __restrict__ bsums, int N) {
  __shared__ int sd[1024];
  int base = blockIdx.x * 1024;
  for (int j = threadIdx.x; j < 1024; j += THREADS) sd[j] = (base + j < N) ? deg[base + j] : 0;
  __syncthreads();
  for (int off = 1; off < 1024; off <<= 1) {
    int v[4];
#pragma unroll
    for (int k = 0; k < 4; ++k) { int j = threadIdx.x + k * THREADS; v[k] = (j >= off) ? sd[j - off] : 0; }
    __syncthreads();
#pragma unroll
    for (int k = 0; k < 4; ++k) { int j = threadIdx.x + k * THREADS; sd[j] += v[k]; }
    __syncthreads();
  }
  for (int j = threadIdx.x; j < 1024; j += THREADS) if (base + j < N) incl[base + j] = sd[j];
  if (threadIdx.x == 0) bsums[blockIdx.x] = sd[1023];
}

__global__ void k_scan2(const int* __restrict__ bsums, int* __restrict__ boffs, int nb) {
  __shared__ int sd[256];
  int t = threadIdx.x;
  sd[t] = (t < nb) ? bsums[t] : 0;
  __syncthreads();
  for (int off = 1; off < 256; off <<= 1) {
    int v = (t >= off) ? sd[t - off] : 0;
    __syncthreads();
    sd[t] += v;
    __syncthreads();
  }
  if (t < nb) boffs[t] = (t == 0) ? 0 : sd[t - 1];
}

__global__ void k_scan3(int* __restrict__ incl_rowptr, const int* __restrict__ deg,
                        const int* __restrict__ boffs, int N, int E) {
  int i = blockIdx.x * blockDim.x + threadIdx.x;
  if (i < N) incl_rowptr[i] = incl_rowptr[i] - deg[i] + boffs[i >> 10];
  if (i == 0) incl_rowptr[N] = E;
}

// ---- chunk-scan: histD[c][v] -> scatter offset base row_ptr[v]+prefix ------
__global__ void k_chunkscan(int* __restrict__ histD, const int* __restrict__ row_ptr, int N) {
  int v = blockIdx.x * blockDim.x + threadIdx.x;
  if (v >= N) return;
  int run = row_ptr[v];
#pragma unroll
  for (int c = 0; c < CHUNKS; ++c) {
    size_t idx = (size_t)c * N + v;
    int t = histD[idx];
    histD[idx] = run;
    run += t;
  }
}

// ---- CSR fill: rank via LDS atomic on range slice of offsets ---------------
__global__ __launch_bounds__(THREADS)
void k_csr(const int* __restrict__ dst, const int* __restrict__ src,
           const int* __restrict__ offs, int* __restrict__ csr_src,
           int N, int E, int ranges) {
  __shared__ int offL[RANGE];
  int r = blockIdx.x % ranges;
  int c = blockIdx.x / ranges;
  int lo = r * RANGE;
  unsigned span = (unsigned)min(RANGE, N - lo);
  int t = threadIdx.x;
  for (int j = t; j < (int)span; j += THREADS) offL[j] = offs[(size_t)c * N + lo + j];
  __syncthreads();

  int beg = (int)((long long)c * E / CHUNKS);
  int end = (int)((long long)(c + 1) * E / CHUNKS);
  int a = min(end, (beg + 3) & ~3);
  for (int i = beg + t; i < a; i += THREADS) {
    unsigned u = (unsigned)(dst[i] - lo);
    if (u < span) csr_src[atomicAdd(&offL[u], 1)] = src[i];
  }
  for (int i4 = a + t * 4; i4 + 3 < end; i4 += THREADS * 4) {
    int4 d = *(const int4*)(dst + i4);
    int4 s = *(const int4*)(src + i4);
    unsigned u0 = (unsigned)(d.x - lo), u1 = (unsigned)(d.y - lo);
    unsigned u2 = (unsigned)(d.z - lo), u3 = (unsigned)(d.w - lo);
    if (u0 < span) csr_src[atomicAdd(&offL[u0], 1)] = s.x;
    if (u1 < span) csr_src[atomicAdd(&offL[u1], 1)] = s.y;
    if (u2 < span) csr_src[atomicAdd(&offL[u2], 1)] = s.z;
    if (u3 < span) csr_src[atomicAdd(&offL[u3], 1)] = s.w;
  }
  int tail = a + ((end - a) & ~3);
  for (int i = tail + t; i < end; i += THREADS) {
    unsigned u = (unsigned)(dst[i] - lo);
    if (u < span) csr_src[atomicAdd(&offL[u], 1)] = src[i];
  }
}

// ---- cast+scale: XS[v] = fp16(x[v] * invout[v]) ----------------------------
__global__ __launch_bounds__(THREADS)
void k_cast_scale(const float4* __restrict__ X, const float* __restrict__ invo,
                  h8* __restrict__ XS, int N) {
  int i = blockIdx.x * blockDim.x + threadIdx.x;   // one h8 (8 floats) each
  if (i >= N * 16) return;
  int row = i >> 4;
  float s = invo[row];
  float4 a = X[(size_t)i * 2];
  float4 b = X[(size_t)i * 2 + 1];
  h8 h;
  h[0] = (_Float16)(a.x * s); h[1] = (_Float16)(a.y * s);
  h[2] = (_Float16)(a.z * s); h[3] = (_Float16)(a.w * s);
  h[4] = (_Float16)(b.x * s); h[5] = (_Float16)(b.y * s);
  h[6] = (_Float16)(b.z * s); h[7] = (_Float16)(b.w * s);
  XS[i] = h;
}

// ---- fp16 CSR aggregation: O[v] = fp16( sum_{e:dst=v} H[src] ) -------------
// invout pre-folded into H. 16 lanes/node x 16B; f32 accumulation, fp16 out.
__global__ __launch_bounds__(THREADS)
void k_agg_h(const h8* __restrict__ H, const int* __restrict__ row_ptr,
             const int* __restrict__ csr_src, h8* __restrict__ O, int N) {
  int g = blockIdx.x * (THREADS / 16) + (threadIdx.x >> 4);
  int lane = threadIdx.x & 15;
  if (g >= N) return;
  int e = row_ptr[g], end = row_ptr[g + 1];
  float sa[8] = {0.f, 0.f, 0.f, 0.f, 0.f, 0.f, 0.f, 0.f};
  float sb[8] = {0.f, 0.f, 0.f, 0.f, 0.f, 0.f, 0.f, 0.f};
  for (; e + 1 < end; e += 2) {
    int n0 = csr_src[e], n1 = csr_src[e + 1];
    h8 v0 = H[(size_t)n0 * 16 + lane];
    h8 v1 = H[(size_t)n1 * 16 + lane];
#pragma unroll
    for (int j = 0; j < 8; ++j) { sa[j] += (float)v0[j]; sb[j] += (float)v1[j]; }
  }
  if (e < end) {
    h8 v0 = H[(size_t)csr_src[e] * 16 + lane];
#pragma unroll
    for (int j = 0; j < 8; ++j) sa[j] += (float)v0[j];
  }
  h8 hv;
#pragma unroll
  for (int j = 0; j < 8; ++j) hv[j] = (_Float16)(sa[j] + sb[j]);
  __builtin_nontemporal_store(hv, &O[(size_t)g * 16 + lane]);
}

// ---- fp16 z-gather (+bout): out[v] = sum z[src] + bout (f32 out) -----------
// z row = 64 fp16 = 8 x h8; 8 lanes/node x 16B; f32 accumulation.
__global__ __launch_bounds__(THREADS)
void k_agg_z(const h8* __restrict__ Z, const int* __restrict__ row_ptr,
             const int* __restrict__ csr_src, const float* __restrict__ bo,
             float4* __restrict__ Out, int N) {
  int g = blockIdx.x * (THREADS / 8) + (threadIdx.x >> 3);
  int lane = threadIdx.x & 7;
  if (g >= N) return;
  int e = row_ptr[g], end = row_ptr[g + 1];
  float sa[8], sb[8] = {0.f, 0.f, 0.f, 0.f, 0.f, 0.f, 0.f, 0.f};
  {
    float4 b0 = ((const float4*)bo)[lane * 2];
    float4 b1 = ((const float4*)bo)[lane * 2 + 1];
    sa[0] = b0.x; sa[1] = b0.y; sa[2] = b0.z; sa[3] = b0.w;
    sa[4] = b1.x; sa[5] = b1.y; sa[6] = b1.z; sa[7] = b1.w;
  }
  for (; e + 1 < end; e += 2) {
    int n0 = csr_src[e], n1 = csr_src[e + 1];
    h8 v0 = Z[(size_t)n0 * 8 + lane];
    h8 v1 = Z[(size_t)n1 * 8 + lane];
#pragma unroll
    for (int j = 0; j < 8; ++j) { sa[j] += (float)v0[j]; sb[j] += (float)v1[j]; }
  }
  if (e < end) {
    h8 v0 = Z[(size_t)csr_src[e] * 8 + lane];
#pragma unroll
    for (int j = 0; j < 8; ++j) sa[j] += (float)v0[j];
  }
  float4 o0 = make_float4(sa[0] + sb[0], sa[1] + sb[1], sa[2] + sb[2], sa[3] + sb[3]);
  float4 o1 = make_float4(sa[4] + sb[4], sa[5] + sb[5], sa[6] + sb[6], sa[7] + sb[7]);
  nt_store_f4(o0, &Out[(size_t)g * 16 + lane * 2]);
  nt_store_f4(o1, &Out[(size_t)g * 16 + lane * 2 + 1]);
}

// ---- MFMA GEMM (layer): H = relu((A@W)*invi + b); emits fp16 H (and H*invo)
template <bool EMIT_S>
__global__ __launch_bounds__(THREADS, 2)
void k_gemm_mfma(const h8* __restrict__ Ah, const float* __restrict__ W,
                 const float* __restrict__ bias, const float* __restrict__ invi,
                 const float* __restrict__ invo,
                 _Float16* __restrict__ Hs, _Float16* __restrict__ Hh, int N) {
  __shared__ _Float16 As[128 * 136];   // [row][k], 272B row stride (17x16B)
  __shared__ _Float16 Ws[128 * 136];   // [col][k] (transposed)
  int t = threadIdx.x;
  int row0 = blockIdx.x * 128;

  {  // stage A: thread -> half-row (64 halfs = 8 x h8)
    int r = t >> 1, hf = t & 1;
    int gr = row0 + r;
    const h8* Arow = Ah + (size_t)gr * 16 + hf * 8;
    h8 z8 = {};
#pragma unroll
    for (int q = 0; q < 8; ++q) {
      h8 v = (gr < N) ? Arow[q] : z8;
      *(h8*)&As[r * 136 + hf * 64 + q * 8] = v;
    }
  }
  {  // stage W transposed, f32 -> fp16
    const float4* Wv = (const float4*)W;
    int n4 = t & 31, kb = t >> 5;
#pragma unroll
    for (int p = 0; p < 16; ++p) {
      int k = kb + p * 8;
      float4 w = Wv[(size_t)k * 32 + n4];
      Ws[(n4 * 4 + 0) * 136 + k] = (_Float16)w.x;
      Ws[(n4 * 4 + 1) * 136 + k] = (_Float16)w.y;
      Ws[(n4 * 4 + 2) * 136 + k] = (_Float16)w.z;
      Ws[(n4 * 4 + 3) * 136 + k] = (_Float16)w.w;
    }
  }
  __syncthreads();

  int wave = t >> 6, lane = t & 63;
  int l15 = lane & 15, lhi = lane >> 4;
  int wr0 = wave * 32;

  h8 a[2][4];
#pragma unroll
  for (int rt = 0; rt < 2; ++rt)
#pragma unroll
    for (int kk = 0; kk < 4; ++kk)
      a[rt][kk] = *(const h8*)&As[(wr0 + rt * 16 + l15) * 136 + kk * 32 + lhi * 8];

  f32x4 acc[2][8] = {};
#pragma unroll
  for (int ct = 0; ct < 8; ++ct) {
    h8 b[4];
#pragma unroll
    for (int kk = 0; kk < 4; ++kk)
      b[kk] = *(const h8*)&Ws[(ct * 16 + l15) * 136 + kk * 32 + lhi * 8];
#pragma unroll
    for (int kk = 0; kk < 4; ++kk) {
      acc[0][ct] = __builtin_amdgcn_mfma_f32_16x16x32_f16(a[0][kk], b[kk], acc[0][ct], 0, 0, 0);
      acc[1][ct] = __builtin_amdgcn_mfma_f32_16x16x32_f16(a[1][kk], b[kk], acc[1][ct], 0, 0, 0);
    }
  }

  float bn[8];
#pragma unroll
  for (int ct = 0; ct < 8; ++ct) bn[ct] = bias[ct * 16 + l15];
#pragma unroll
  for (int rt = 0; rt < 2; ++rt) {
#pragma unroll
    for (int reg = 0; reg < 4; ++reg) {
      int m = row0 + wr0 + rt * 16 + lhi * 4 + reg;
      if (m < N) {
        float si = invi[m];
        float so = EMIT_S ? invo[m] : 0.f;
#pragma unroll
        for (int ct = 0; ct < 8; ++ct) {
          int n = ct * 16 + l15;
          float o = fmaxf(acc[rt][ct][reg] * si + bn[ct], 0.f);
          Hh[(size_t)m * 128 + n] = (_Float16)o;
          if (EMIT_S) Hs[(size_t)m * 128 + n] = (_Float16)(o * so);
        }
      }
    }
  }
}

// ---- MFMA z GEMM: Z = fp16(H1@Wo[0:128] + H2@Wo[128:256]) (N x 64) ---------
__global__ __launch_bounds__(THREADS, 2)
void k_gemm_z(const h8* __restrict__ H1, const h8* __restrict__ H2,
              const float* __restrict__ Wo, _Float16* __restrict__ Z, int N) {
  __shared__ _Float16 As[128 * 136];   // [row][k]
  __shared__ _Float16 Ws[64 * 136];    // [col][k]
  int t = threadIdx.x;
  int row0 = blockIdx.x * 128;
  int wave = t >> 6, lane = t & 63;
  int l15 = lane & 15, lhi = lane >> 4;
  int wr0 = wave * 32;

  f32x4 acc[2][4] = {};
#pragma unroll 1
  for (int hf = 0; hf < 2; ++hf) {
    if (hf) __syncthreads();           // all reads of As/Ws done
    {
      int r = t >> 1, rh = t & 1;
      int gr = row0 + r;
      const h8* Asrc = (hf ? H2 : H1) + (size_t)gr * 16 + rh * 8;
      h8 z8 = {};
#pragma unroll
      for (int q = 0; q < 8; ++q) {
        h8 v = (gr < N) ? Asrc[q] : z8;
        *(h8*)&As[r * 136 + rh * 64 + q * 8] = v;
      }
    }
    {
      const float4* Wv = (const float4*)Wo;
      int n4 = t & 15, kb = t >> 4;
#pragma unroll
      for (int p = 0; p < 8; ++p) {
        int k = kb + p * 16;
        float4 w = Wv[(size_t)(hf * 128 + k) * 16 + n4];
        Ws[(n4 * 4 + 0) * 136 + k] = (_Float16)w.x;
        Ws[(n4 * 4 + 1) * 136 + k] = (_Float16)w.y;
        Ws[(n4 * 4 + 2) * 136 + k] = (_Float16)w.z;
        Ws[(n4 * 4 + 3) * 136 + k] = (_Float16)w.w;
      }
    }
    __syncthreads();

    h8 a[2][4];
#pragma unroll
    for (int rt = 0; rt < 2; ++rt)
#pragma unroll
      for (int kk = 0; kk < 4; ++kk)
        a[rt][kk] = *(const h8*)&As[(wr0 + rt * 16 + l15) * 136 + kk * 32 + lhi * 8];
#pragma unroll
    for (int ct = 0; ct < 4; ++ct) {
      h8 b[4];
#pragma unroll
      for (int kk = 0; kk < 4; ++kk)
        b[kk] = *(const h8*)&Ws[(ct * 16 + l15) * 136 + kk * 32 + lhi * 8];
#pragma unroll
      for (int kk = 0; kk < 4; ++kk) {
        acc[0][ct] = __builtin_amdgcn_mfma_f32_16x16x32_f16(a[0][kk], b[kk], acc[0][ct], 0, 0, 0);
        acc[1][ct] = __builtin_amdgcn_mfma_f32_16x16x32_f16(a[1][kk], b[kk], acc[1][ct], 0, 0, 0);
      }
    }
  }

#pragma unroll
  for (int rt = 0; rt < 2; ++rt) {
#pragma unroll
    for (int reg = 0; reg < 4; ++reg) {
      int m = row0 + wr0 + rt * 16 + lhi * 4 + reg;
      if (m < N) {
#pragma unroll
        for (int ct = 0; ct < 4; ++ct) {
          int n = ct * 16 + l15;
          Z[(size_t)m * 64 + n] = (_Float16)acc[rt][ct][reg];
        }
      }
    }
  }
}

// ---------------------------------------------------------------------------
extern "C" void kernel_launch(void* const* d_in, const int* in_sizes, int n_in,
                              void* d_out, int out_size, void* d_ws, size_t ws_size,
                              hipStream_t stream) {
  const float* x    = (const float*)d_in[0];
  const int*   src  = (const int*)d_in[1];
  const int*   dst  = (const int*)d_in[2];
  const float* W1   = (const float*)d_in[3];
  const float* b1   = (const float*)d_in[4];
  const float* W2   = (const float*)d_in[5];
  const float* b2   = (const float*)d_in[6];
  const float* Wout = (const float*)d_in[7];
  const float* bout = (const float*)d_in[8];
  float* out = (float*)d_out;

  const int IN = 128;
  const int N = in_sizes[0] / IN;   // 100000
  const int E = in_sizes[1];        // 1600000
  const int ranges = (N + RANGE - 1) / RANGE;  // 4

  char* p = (char*)d_ws;
  auto alloc = [&](size_t bytes) -> char* {
    char* r = p;
    p += (bytes + 255) & ~(size_t)255;
    return r;
  };
  int* histD = (int*)alloc((size_t)CHUNKS * N * 4);   // also scatter offsets
  int* histS = (int*)alloc((size_t)CHUNKS * N * 4);
  h8* bZ = (h8*)alloc((size_t)N * 64 * 2);   // z (fp16, N x 64)
  h8* bX = (h8*)alloc((size_t)N * 128 * 2);  // xs, then aggB
  h8* bA = (h8*)alloc((size_t)N * 128 * 2);  // aggA, then h2h
  h8* bS = (h8*)alloc((size_t)N * 128 * 2);  // h1s
  h8* bH = (h8*)alloc((size_t)N * 128 * 2);  // h1h
  float* invo   = (float*)alloc((size_t)N * 4);
  float* invi   = (float*)alloc((size_t)N * 4);
  int* deg_i    = (int*)alloc((size_t)N * 4);
  int* row_ptr  = (int*)alloc((size_t)(N + 1) * 4);
  int* bsums    = (int*)alloc(1024);
  int* boffs    = (int*)alloc(1024);
  int* csr_src  = (int*)alloc((size_t)E * 4);

  // ---- CSR build: no global atomics ---------------------------------------
  k_hist<<<ranges * CHUNKS * 2, THREADS, 0, stream>>>(dst, src, histD, histS, N, E, ranges);
  k_redinv<<<(N + THREADS - 1) / THREADS, THREADS, 0, stream>>>(histD, histS, deg_i, invi, invo, N);
  int nb1 = (N + 1023) / 1024;
  k_scan1<<<nb1, THREADS, 0, stream>>>(deg_i, row_ptr, bsums, N);
  k_scan2<<<1, 256, 0, stream>>>(bsums, boffs, nb1);
  k_scan3<<<(N + THREADS - 1) / THREADS, THREADS, 0, stream>>>(row_ptr, deg_i, boffs, N, E);
  k_chunkscan<<<(N + THREADS - 1) / THREADS, THREADS, 0, stream>>>(histD, row_ptr, N);
  k_csr<<<ranges * CHUNKS, THREADS, 0, stream>>>(dst, src, histD, csr_src, N, E, ranges);

  const int aggGrid  = (N + (THREADS / 16) - 1) / (THREADS / 16);
  const int aggzGrid = (N + (THREADS / 8) - 1) / (THREADS / 8);
  const int gemmGrid = (N + 127) / 128;
  const int castGrid = (N * 16 + THREADS - 1) / THREADS;

  // ---- layer 1 -------------------------------------------------------------
  k_cast_scale<<<castGrid, THREADS, 0, stream>>>((const float4*)x, invo, bX, N);
  k_agg_h<<<aggGrid, THREADS, 0, stream>>>(bX, row_ptr, csr_src, bA, N);        // aggA
  k_gemm_mfma<true><<<gemmGrid, THREADS, 0, stream>>>(bA, W1, b1, invi, invo,
                                                      (_Float16*)bS, (_Float16*)bH, N);

  // ---- layer 2 -------------------------------------------------------------
  k_agg_h<<<aggGrid, THREADS, 0, stream>>>(bS, row_ptr, csr_src, bX, N);        // aggB (xs dead)
  k_gemm_mfma<false><<<gemmGrid, THREADS, 0, stream>>>(bX, W2, b2, invi, invo,
                                                       nullptr, (_Float16*)bA, N);  // h2h

  // ---- z = fp16(h1h@Wo1 + h2h@Wo2) then out = A@z + bout -------------------
  k_gemm_z<<<gemmGrid, THREADS, 0, stream>>>(bH, bA, Wout, (_Float16*)bZ, N);
  k_agg_z<<<aggzGrid, THREADS, 0, stream>>>(bZ, row_ptr, csr_src, bout, (float4*)out, N);
}

// Round 11
// 458.629 us; speedup vs baseline: 1.1050x; 1.1050x over previous
//
#include <hip/hip_runtime.h>
#include <cstddef>
#include <cstdint>

// ---------------------------------------------------------------------------
// JKNet, aggregate-first + fp16 hidden states + MFMA GEMMs.
//   xs = fp16(x*invo);           aggA = A@xs (fp16 out)
//   h1 = relu((aggA@W1)*invi+b1) via MFMA; emits h1s=fp16(h1*invo), h1h=fp16(h1)
//   aggB = A@h1s (fp16 out);     h2h = fp16(relu((aggB@W2)*invi+b2)) via MFMA
//   z = fp16(h1h@Wo1 + h2h@Wo2) via MFMA;  out[v] = sum z[src] + bout (f32)
// R9 lesson: build kernels are PARALLELISM-bound (need grid >= 256 blocks),
//     not side-traffic-bound. CHUNKS=16 gave k_csr a 64-block grid -> 86us.
// R10: CHUNKS=64 (k_csr/k_hist grids = 256 blocks = 1/CU); histogram split
//     into two sequential passes (src -> invo, then dst -> deg/invi/offsets)
//     reusing ONE 25.6MB hist buffer so workspace stays ~148MB.
// ---------------------------------------------------------------------------

#define THREADS 256
#define RANGE 25600      // nodes per LDS histogram slice (100 KB LDS)
#define CHUNKS 64        // edge chunks

typedef float f32x4 __attribute__((ext_vector_type(4)));
typedef _Float16 h8 __attribute__((ext_vector_type(8)));

__device__ __forceinline__ void nt_store_f4(const float4 s, float4* dst) {
  f32x4 v; v.x = s.x; v.y = s.y; v.z = s.z; v.w = s.w;
  __builtin_nontemporal_store(v, (f32x4*)dst);
}

// ---- 2D histogram (one key array): hist[c][v] = #edges in chunk c, key==v --
__global__ __launch_bounds__(THREADS)
void k_hist(const int* __restrict__ arr, int* __restrict__ hist,
            int N, int E, int ranges) {
  __shared__ int h[RANGE];
  int r = blockIdx.x % ranges;
  int c = blockIdx.x / ranges;
  int lo = r * RANGE;
  unsigned span = (unsigned)min(RANGE, N - lo);
  int t = threadIdx.x;
  for (int j = t; j < RANGE; j += THREADS) h[j] = 0;
  __syncthreads();

  int beg = (int)((long long)c * E / CHUNKS);
  int end = (int)((long long)(c + 1) * E / CHUNKS);
  int a = min(end, (beg + 3) & ~3);
  for (int i = beg + t; i < a; i += THREADS) {
    unsigned u = (unsigned)(arr[i] - lo);
    if (u < span) atomicAdd(&h[u], 1);
  }
  for (int i4 = a + t * 4; i4 + 3 < end; i4 += THREADS * 4) {
    int4 v = *(const int4*)(arr + i4);
    unsigned u0 = (unsigned)(v.x - lo), u1 = (unsigned)(v.y - lo);
    unsigned u2 = (unsigned)(v.z - lo), u3 = (unsigned)(v.w - lo);
    if (u0 < span) atomicAdd(&h[u0], 1);
    if (u1 < span) atomicAdd(&h[u1], 1);
    if (u2 < span) atomicAdd(&h[u2], 1);
    if (u3 < span) atomicAdd(&h[u3], 1);
  }
  int tail = a + ((end - a) & ~3);
  for (int i = tail + t; i < end; i += THREADS) {
    unsigned u = (unsigned)(arr[i] - lo);
    if (u < span) atomicAdd(&h[u], 1);
  }
  __syncthreads();
  for (int j = t; j < (int)span; j += THREADS) hist[(size_t)c * N + lo + j] = h[j];
}

// ---- reduce hist columns -> invo (from src-hist) ---------------------------
__global__ void k_red_invo(const int* __restrict__ hist, float* __restrict__ inv_out, int N) {
  int v = blockIdx.x * blockDim.x + threadIdx.x;
  if (v >= N) return;
  int s = 0;
#pragma unroll
  for (int c = 0; c < CHUNKS; ++c) s += hist[(size_t)c * N + v];
  inv_out[v] = rsqrtf((float)max(s, 1));
}

// ---- reduce hist columns -> deg_i, invi (from dst-hist) --------------------
__global__ void k_red_degi(const int* __restrict__ hist, int* __restrict__ deg_i,
                           float* __restrict__ inv_in, int N) {
  int v = blockIdx.x * blockDim.x + threadIdx.x;
  if (v >= N) return;
  int s = 0;
#pragma unroll
  for (int c = 0; c < CHUNKS; ++c) s += hist[(size_t)c * N + v];
  deg_i[v] = s;
  inv_in[v] = rsqrtf((float)max(s, 1));
}

// ---- exclusive scan of deg_i -> row_ptr (3 kernels, chunk=1024) ------------
__global__ void k_scan1(const int* __restrict__ deg, int* __restrict__ incl,
                        int* __restrict__ bsums, int N) {
  __shared__ int sd[1024];
  int base = blockIdx.x * 1024;
  for (int j = threadIdx.x; j < 1024; j += THREADS) sd[j] = (base + j < N) ? deg[base + j] : 0;
  __syncthreads();
  for (int off = 1; off < 1024; off <<= 1) {
    int v[4];
#pragma unroll
    for (int k = 0; k < 4; ++k) { int j = threadIdx.x + k * THREADS; v[k] = (j >= off) ? sd[j - off] : 0; }
    __syncthreads();
#pragma unroll
    for (int k = 0; k < 4; ++k) { int j = threadIdx.x + k * THREADS; sd[j] += v[k]; }
    __syncthreads();
  }
  for (int j = threadIdx.x; j < 1024; j += THREADS) if (base + j < N) incl[base + j] = sd[j];
  if (threadIdx.x == 0) bsums[blockIdx.x] = sd[1023];
}

__global__ void k_scan2(const int* __restrict__ bsums, int* __restrict__ boffs, int nb) {
  __shared__ int sd[256];
  int t = threadIdx.x;
  sd[t] = (t < nb) ? bsums[t] : 0;
  __syncthreads();
  for (int off = 1; off < 256; off <<= 1) {
    int v = (t >= off) ? sd[t - off] : 0;
    __syncthreads();
    sd[t] += v;
    __syncthreads();
  }
  if (t < nb) boffs[t] = (t == 0) ? 0 : sd[t - 1];
}

__global__ void k_scan3(int* __restrict__ incl_rowptr, const int* __restrict__ deg,
                        const int* __restrict__ boffs, int N, int E) {
  int i = blockIdx.x * blockDim.x + threadIdx.x;
  if (i < N) incl_rowptr[i] = incl_rowptr[i] - deg[i] + boffs[i >> 10];
  if (i == 0) incl_rowptr[N] = E;
}

// ---- chunk-scan: hist[c][v] -> scatter offset base row_ptr[v]+prefix -------
__global__ void k_chunkscan(int* __restrict__ hist, const int* __restrict__ row_ptr, int N) {
  int v = blockIdx.x * blockDim.x + threadIdx.x;
  if (v >= N) return;
  int run = row_ptr[v];
#pragma unroll
  for (int c = 0; c < CHUNKS; ++c) {
    size_t idx = (size_t)c * N + v;
    int t = hist[idx];
    hist[idx] = run;
    run += t;
  }
}

// ---- CSR fill: rank via LDS atomic on range slice of offsets ---------------
__global__ __launch_bounds__(THREADS)
void k_csr(const int* __restrict__ dst, const int* __restrict__ src,
           const int* __restrict__ offs, int* __restrict__ csr_src,
           int N, int E, int ranges) {
  __shared__ int offL[RANGE];
  int r = blockIdx.x % ranges;
  int c = blockIdx.x / ranges;
  int lo = r * RANGE;
  unsigned span = (unsigned)min(RANGE, N - lo);
  int t = threadIdx.x;
  for (int j = t; j < (int)span; j += THREADS) offL[j] = offs[(size_t)c * N + lo + j];
  __syncthreads();

  int beg = (int)((long long)c * E / CHUNKS);
  int end = (int)((long long)(c + 1) * E / CHUNKS);
  int a = min(end, (beg + 3) & ~3);
  for (int i = beg + t; i < a; i += THREADS) {
    unsigned u = (unsigned)(dst[i] - lo);
    if (u < span) csr_src[atomicAdd(&offL[u], 1)] = src[i];
  }
  for (int i4 = a + t * 4; i4 + 3 < end; i4 += THREADS * 4) {
    int4 d = *(const int4*)(dst + i4);
    int4 s = *(const int4*)(src + i4);
    unsigned u0 = (unsigned)(d.x - lo), u1 = (unsigned)(d.y - lo);
    unsigned u2 = (unsigned)(d.z - lo), u3 = (unsigned)(d.w - lo);
    if (u0 < span) csr_src[atomicAdd(&offL[u0], 1)] = s.x;
    if (u1 < span) csr_src[atomicAdd(&offL[u1], 1)] = s.y;
    if (u2 < span) csr_src[atomicAdd(&offL[u2], 1)] = s.z;
    if (u3 < span) csr_src[atomicAdd(&offL[u3], 1)] = s.w;
  }
  int tail = a + ((end - a) & ~3);
  for (int i = tail + t; i < end; i += THREADS) {
    unsigned u = (unsigned)(dst[i] - lo);
    if (u < span) csr_src[atomicAdd(&offL[u], 1)] = src[i];
  }
}

// ---- cast+scale: XS[v] = fp16(x[v] * invout[v]) ----------------------------
__global__ __launch_bounds__(THREADS)
void k_cast_scale(const float4* __restrict__ X, const float* __restrict__ invo,
                  h8* __restrict__ XS, int N) {
  int i = blockIdx.x * blockDim.x + threadIdx.x;   // one h8 (8 floats) each
  if (i >= N * 16) return;
  int row = i >> 4;
  float s = invo[row];
  float4 a = X[(size_t)i * 2];
  float4 b = X[(size_t)i * 2 + 1];
  h8 h;
  h[0] = (_Float16)(a.x * s); h[1] = (_Float16)(a.y * s);
  h[2] = (_Float16)(a.z * s); h[3] = (_Float16)(a.w * s);
  h[4] = (_Float16)(b.x * s); h[5] = (_Float16)(b.y * s);
  h[6] = (_Float16)(b.z * s); h[7] = (_Float16)(b.w * s);
  XS[i] = h;
}

// ---- fp16 CSR aggregation: O[v] = fp16( sum_{e:dst=v} H[src] ) -------------
__global__ __launch_bounds__(THREADS)
void k_agg_h(const h8* __restrict__ H, const int* __restrict__ row_ptr,
             const int* __restrict__ csr_src, h8* __restrict__ O, int N) {
  int g = blockIdx.x * (THREADS / 16) + (threadIdx.x >> 4);
  int lane = threadIdx.x & 15;
  if (g >= N) return;
  int e = row_ptr[g], end = row_ptr[g + 1];
  float sa[8] = {0.f, 0.f, 0.f, 0.f, 0.f, 0.f, 0.f, 0.f};
  float sb[8] = {0.f, 0.f, 0.f, 0.f, 0.f, 0.f, 0.f, 0.f};
  for (; e + 1 < end; e += 2) {
    int n0 = csr_src[e], n1 = csr_src[e + 1];
    h8 v0 = H[(size_t)n0 * 16 + lane];
    h8 v1 = H[(size_t)n1 * 16 + lane];
#pragma unroll
    for (int j = 0; j < 8; ++j) { sa[j] += (float)v0[j]; sb[j] += (float)v1[j]; }
  }
  if (e < end) {
    h8 v0 = H[(size_t)csr_src[e] * 16 + lane];
#pragma unroll
    for (int j = 0; j < 8; ++j) sa[j] += (float)v0[j];
  }
  h8 hv;
#pragma unroll
  for (int j = 0; j < 8; ++j) hv[j] = (_Float16)(sa[j] + sb[j]);
  __builtin_nontemporal_store(hv, &O[(size_t)g * 16 + lane]);
}

// ---- fp16 z-gather (+bout): out[v] = sum z[src] + bout (f32 out) -----------
__global__ __launch_bounds__(THREADS)
void k_agg_z(const h8* __restrict__ Z, const int* __restrict__ row_ptr,
             const int* __restrict__ csr_src, const float* __restrict__ bo,
             float4* __restrict__ Out, int N) {
  int g = blockIdx.x * (THREADS / 8) + (threadIdx.x >> 3);
  int lane = threadIdx.x & 7;
  if (g >= N) return;
  int e = row_ptr[g], end = row_ptr[g + 1];
  float sa[8], sb[8] = {0.f, 0.f, 0.f, 0.f, 0.f, 0.f, 0.f, 0.f};
  {
    float4 b0 = ((const float4*)bo)[lane * 2];
    float4 b1 = ((const float4*)bo)[lane * 2 + 1];
    sa[0] = b0.x; sa[1] = b0.y; sa[2] = b0.z; sa[3] = b0.w;
    sa[4] = b1.x; sa[5] = b1.y; sa[6] = b1.z; sa[7] = b1.w;
  }
  for (; e + 1 < end; e += 2) {
    int n0 = csr_src[e], n1 = csr_src[e + 1];
    h8 v0 = Z[(size_t)n0 * 8 + lane];
    h8 v1 = Z[(size_t)n1 * 8 + lane];
#pragma unroll
    for (int j = 0; j < 8; ++j) { sa[j] += (float)v0[j]; sb[j] += (float)v1[j]; }
  }
  if (e < end) {
    h8 v0 = Z[(size_t)csr_src[e] * 8 + lane];
#pragma unroll
    for (int j = 0; j < 8; ++j) sa[j] += (float)v0[j];
  }
  float4 o0 = make_float4(sa[0] + sb[0], sa[1] + sb[1], sa[2] + sb[2], sa[3] + sb[3]);
  float4 o1 = make_float4(sa[4] + sb[4], sa[5] + sb[5], sa[6] + sb[6], sa[7] + sb[7]);
  nt_store_f4(o0, &Out[(size_t)g * 16 + lane * 2]);
  nt_store_f4(o1, &Out[(size_t)g * 16 + lane * 2 + 1]);
}

// ---- MFMA GEMM (layer): H = relu((A@W)*invi + b); emits fp16 H (and H*invo)
template <bool EMIT_S>
__global__ __launch_bounds__(THREADS, 2)
void k_gemm_mfma(const h8* __restrict__ Ah, const float* __restrict__ W,
                 const float* __restrict__ bias, const float* __restrict__ invi,
                 const float* __restrict__ invo,
                 _Float16* __restrict__ Hs, _Float16* __restrict__ Hh, int N) {
  __shared__ _Float16 As[128 * 136];   // [row][k], 272B row stride (17x16B)
  __shared__ _Float16 Ws[128 * 136];   // [col][k] (transposed)
  int t = threadIdx.x;
  int row0 = blockIdx.x * 128;

  {  // stage A: thread -> half-row (64 halfs = 8 x h8)
    int r = t >> 1, hf = t & 1;
    int gr = row0 + r;
    const h8* Arow = Ah + (size_t)gr * 16 + hf * 8;
    h8 z8 = {};
#pragma unroll
    for (int q = 0; q < 8; ++q) {
      h8 v = (gr < N) ? Arow[q] : z8;
      *(h8*)&As[r * 136 + hf * 64 + q * 8] = v;
    }
  }
  {  // stage W transposed, f32 -> fp16
    const float4* Wv = (const float4*)W;
    int n4 = t & 31, kb = t >> 5;
#pragma unroll
    for (int p = 0; p < 16; ++p) {
      int k = kb + p * 8;
      float4 w = Wv[(size_t)k * 32 + n4];
      Ws[(n4 * 4 + 0) * 136 + k] = (_Float16)w.x;
      Ws[(n4 * 4 + 1) * 136 + k] = (_Float16)w.y;
      Ws[(n4 * 4 + 2) * 136 + k] = (_Float16)w.z;
      Ws[(n4 * 4 + 3) * 136 + k] = (_Float16)w.w;
    }
  }
  __syncthreads();

  int wave = t >> 6, lane = t & 63;
  int l15 = lane & 15, lhi = lane >> 4;
  int wr0 = wave * 32;

  h8 a[2][4];
#pragma unroll
  for (int rt = 0; rt < 2; ++rt)
#pragma unroll
    for (int kk = 0; kk < 4; ++kk)
      a[rt][kk] = *(const h8*)&As[(wr0 + rt * 16 + l15) * 136 + kk * 32 + lhi * 8];

  f32x4 acc[2][8] = {};
#pragma unroll
  for (int ct = 0; ct < 8; ++ct) {
    h8 b[4];
#pragma unroll
    for (int kk = 0; kk < 4; ++kk)
      b[kk] = *(const h8*)&Ws[(ct * 16 + l15) * 136 + kk * 32 + lhi * 8];
#pragma unroll
    for (int kk = 0; kk < 4; ++kk) {
      acc[0][ct] = __builtin_amdgcn_mfma_f32_16x16x32_f16(a[0][kk], b[kk], acc[0][ct], 0, 0, 0);
      acc[1][ct] = __builtin_amdgcn_mfma_f32_16x16x32_f16(a[1][kk], b[kk], acc[1][ct], 0, 0, 0);
    }
  }

  float bn[8];
#pragma unroll
  for (int ct = 0; ct < 8; ++ct) bn[ct] = bias[ct * 16 + l15];
#pragma unroll
  for (int rt = 0; rt < 2; ++rt) {
#pragma unroll
    for (int reg = 0; reg < 4; ++reg) {
      int m = row0 + wr0 + rt * 16 + lhi * 4 + reg;
      if (m < N) {
        float si = invi[m];
        float so = EMIT_S ? invo[m] : 0.f;
#pragma unroll
        for (int ct = 0; ct < 8; ++ct) {
          int n = ct * 16 + l15;
          float o = fmaxf(acc[rt][ct][reg] * si + bn[ct], 0.f);
          Hh[(size_t)m * 128 + n] = (_Float16)o;
          if (EMIT_S) Hs[(size_t)m * 128 + n] = (_Float16)(o * so);
        }
      }
    }
  }
}

// ---- MFMA z GEMM: Z = fp16(H1@Wo[0:128] + H2@Wo[128:256]) (N x 64) ---------
__global__ __launch_bounds__(THREADS, 2)
void k_gemm_z(const h8* __restrict__ H1, const h8* __restrict__ H2,
              const float* __restrict__ Wo, _Float16* __restrict__ Z, int N) {
  __shared__ _Float16 As[128 * 136];   // [row][k]
  __shared__ _Float16 Ws[64 * 136];    // [col][k]
  int t = threadIdx.x;
  int row0 = blockIdx.x * 128;
  int wave = t >> 6, lane = t & 63;
  int l15 = lane & 15, lhi = lane >> 4;
  int wr0 = wave * 32;

  f32x4 acc[2][4] = {};
#pragma unroll 1
  for (int hf = 0; hf < 2; ++hf) {
    if (hf) __syncthreads();           // all reads of As/Ws done
    {
      int r = t >> 1, rh = t & 1;
      int gr = row0 + r;
      const h8* Asrc = (hf ? H2 : H1) + (size_t)gr * 16 + rh * 8;
      h8 z8 = {};
#pragma unroll
      for (int q = 0; q < 8; ++q) {
        h8 v = (gr < N) ? Asrc[q] : z8;
        *(h8*)&As[r * 136 + rh * 64 + q * 8] = v;
      }
    }
    {
      const float4* Wv = (const float4*)Wo;
      int n4 = t & 15, kb = t >> 4;
#pragma unroll
      for (int p = 0; p < 8; ++p) {
        int k = kb + p * 16;
        float4 w = Wv[(size_t)(hf * 128 + k) * 16 + n4];
        Ws[(n4 * 4 + 0) * 136 + k] = (_Float16)w.x;
        Ws[(n4 * 4 + 1) * 136 + k] = (_Float16)w.y;
        Ws[(n4 * 4 + 2) * 136 + k] = (_Float16)w.z;
        Ws[(n4 * 4 + 3) * 136 + k] = (_Float16)w.w;
      }
    }
    __syncthreads();

    h8 a[2][4];
#pragma unroll
    for (int rt = 0; rt < 2; ++rt)
#pragma unroll
      for (int kk = 0; kk < 4; ++kk)
        a[rt][kk] = *(const h8*)&As[(wr0 + rt * 16 + l15) * 136 + kk * 32 + lhi * 8];
#pragma unroll
    for (int ct = 0; ct < 4; ++ct) {
      h8 b[4];
#pragma unroll
      for (int kk = 0; kk < 4; ++kk)
        b[kk] = *(const h8*)&Ws[(ct * 16 + l15) * 136 + kk * 32 + lhi * 8];
#pragma unroll
      for (int kk = 0; kk < 4; ++kk) {
        acc[0][ct] = __builtin_amdgcn_mfma_f32_16x16x32_f16(a[0][kk], b[kk], acc[0][ct], 0, 0, 0);
        acc[1][ct] = __builtin_amdgcn_mfma_f32_16x16x32_f16(a[1][kk], b[kk], acc[1][ct], 0, 0, 0);
      }
    }
  }

#pragma unroll
  for (int rt = 0; rt < 2; ++rt) {
#pragma unroll
    for (int reg = 0; reg < 4; ++reg) {
      int m = row0 + wr0 + rt * 16 + lhi * 4 + reg;
      if (m < N) {
#pragma unroll
        for (int ct = 0; ct < 4; ++ct) {
          int n = ct * 16 + l15;
          Z[(size_t)m * 64 + n] = (_Float16)acc[rt][ct][reg];
        }
      }
    }
  }
}

// ---------------------------------------------------------------------------
extern "C" void kernel_launch(void* const* d_in, const int* in_sizes, int n_in,
                              void* d_out, int out_size, void* d_ws, size_t ws_size,
                              hipStream_t stream) {
  const float* x    = (const float*)d_in[0];
  const int*   src  = (const int*)d_in[1];
  const int*   dst  = (const int*)d_in[2];
  const float* W1   = (const float*)d_in[3];
  const float* b1   = (const float*)d_in[4];
  const float* W2   = (const float*)d_in[5];
  const float* b2   = (const float*)d_in[6];
  const float* Wout = (const float*)d_in[7];
  const float* bout = (const float*)d_in[8];
  float* out = (float*)d_out;

  const int IN = 128;
  const int N = in_sizes[0] / IN;   // 100000
  const int E = in_sizes[1];        // 1600000
  const int ranges = (N + RANGE - 1) / RANGE;  // 4

  char* p = (char*)d_ws;
  auto alloc = [&](size_t bytes) -> char* {
    char* r = p;
    p += (bytes + 255) & ~(size_t)255;
    return r;
  };
  int* hist = (int*)alloc((size_t)CHUNKS * N * 4);   // src-hist, then dst-hist/offsets
  h8* bZ = (h8*)alloc((size_t)N * 64 * 2);   // z (fp16, N x 64)
  h8* bX = (h8*)alloc((size_t)N * 128 * 2);  // xs, then aggB
  h8* bA = (h8*)alloc((size_t)N * 128 * 2);  // aggA, then h2h
  h8* bS = (h8*)alloc((size_t)N * 128 * 2);  // h1s
  h8* bH = (h8*)alloc((size_t)N * 128 * 2);  // h1h
  float* invo   = (float*)alloc((size_t)N * 4);
  float* invi   = (float*)alloc((size_t)N * 4);
  int* deg_i    = (int*)alloc((size_t)N * 4);
  int* row_ptr  = (int*)alloc((size_t)(N + 1) * 4);
  int* bsums    = (int*)alloc(1024);
  int* boffs    = (int*)alloc(1024);
  int* csr_src  = (int*)alloc((size_t)E * 4);

  const int nThread = (N + THREADS - 1) / THREADS;

  // ---- CSR build: no global atomics, one hist buffer reused ----------------
  k_hist<<<ranges * CHUNKS, THREADS, 0, stream>>>(src, hist, N, E, ranges);
  k_red_invo<<<nThread, THREADS, 0, stream>>>(hist, invo, N);
  k_hist<<<ranges * CHUNKS, THREADS, 0, stream>>>(dst, hist, N, E, ranges);
  k_red_degi<<<nThread, THREADS, 0, stream>>>(hist, deg_i, invi, N);
  int nb1 = (N + 1023) / 1024;
  k_scan1<<<nb1, THREADS, 0, stream>>>(deg_i, row_ptr, bsums, N);
  k_scan2<<<1, 256, 0, stream>>>(bsums, boffs, nb1);
  k_scan3<<<nThread, THREADS, 0, stream>>>(row_ptr, deg_i, boffs, N, E);
  k_chunkscan<<<nThread, THREADS, 0, stream>>>(hist, row_ptr, N);
  k_csr<<<ranges * CHUNKS, THREADS, 0, stream>>>(dst, src, hist, csr_src, N, E, ranges);

  const int aggGrid  = (N + (THREADS / 16) - 1) / (THREADS / 16);
  const int aggzGrid = (N + (THREADS / 8) - 1) / (THREADS / 8);
  const int gemmGrid = (N + 127) / 128;
  const int castGrid = (N * 16 + THREADS - 1) / THREADS;

  // ---- layer 1 -------------------------------------------------------------
  k_cast_scale<<<castGrid, THREADS, 0, stream>>>((const float4*)x, invo, bX, N);
  k_agg_h<<<aggGrid, THREADS, 0, stream>>>(bX, row_ptr, csr_src, bA, N);        // aggA
  k_gemm_mfma<true><<<gemmGrid, THREADS, 0, stream>>>(bA, W1, b1, invi, invo,
                                                      (_Float16*)bS, (_Float16*)bH, N);

  // ---- layer 2 -------------------------------------------------------------
  k_agg_h<<<aggGrid, THREADS, 0, stream>>>(bS, row_ptr, csr_src, bX, N);        // aggB (xs dead)
  k_gemm_mfma<false><<<gemmGrid, THREADS, 0, stream>>>(bX, W2, b2, invi, invo,
                                                       nullptr, (_Float16*)bA, N);  // h2h

  // ---- z = fp16(h1h@Wo1 + h2h@Wo2) then out = A@z + bout -------------------
  k_gemm_z<<<gemmGrid, THREADS, 0, stream>>>(bH, bA, Wout, (_Float16*)bZ, N);
  k_agg_z<<<aggzGrid, THREADS, 0, stream>>>(bZ, row_ptr, csr_src, bout, (float4*)out, N);
}

// Round 14
// 451.369 us; speedup vs baseline: 1.1228x; 1.0161x over previous
//
#include <hip/hip_runtime.h>
#include <cstddef>
#include <cstdint>

// ---------------------------------------------------------------------------
// JKNet, aggregate-first + fp16 hidden states + MFMA GEMMs.
//   xs = fp16(x*invo);            aggA = A@xs            (gather, 4 lines/edge)
//   h1 = relu((aggA@W1)*invi+b1)  via MFMA -> h1h fp16
//   aggB = A@(h1h*invo[src])      (gather, SCALE on the fly; invo L2-resident)
//   h2h = fp16(relu((aggB@W2)*invi+b2)) via MFMA
//   z = fp16(h1h@Wo1 + h2h@Wo2);  out[v] = sum z[src] + bout (2 lines/edge)
// Measured model: gathers are LINE-REQUEST-RATE bound (~107K lines/us both in
// f32-R6 and fp16-R8) -> duration ~ lines/row. fp16 128-row = 4 lines.
// R11: drop h1s table (scale in gather; -25.6MB gemm1 write, -1 buffer);
//      fuse scan3 into chunkscan (one fewer N-pass + launch).
// R12/R13: resubmits of R11 (bench infra timeouts; no measurement taken).
// ---------------------------------------------------------------------------

#define THREADS 256
#define RANGE 25600      // nodes per LDS histogram slice (100 KB LDS)
#define CHUNKS 64        // edge chunks (k_hist/k_csr grids = 256 blocks)

typedef float f32x4 __attribute__((ext_vector_type(4)));
typedef _Float16 h8 __attribute__((ext_vector_type(8)));

__device__ __forceinline__ void nt_store_f4(const float4 s, float4* dst) {
  f32x4 v; v.x = s.x; v.y = s.y; v.z = s.z; v.w = s.w;
  __builtin_nontemporal_store(v, (f32x4*)dst);
}

// ---- 2D histogram (one key array): hist[c][v] = #edges in chunk c, key==v --
__global__ __launch_bounds__(THREADS)
void k_hist(const int* __restrict__ arr, int* __restrict__ hist,
            int N, int E, int ranges) {
  __shared__ int h[RANGE];
  int r = blockIdx.x % ranges;
  int c = blockIdx.x / ranges;
  int lo = r * RANGE;
  unsigned span = (unsigned)min(RANGE, N - lo);
  int t = threadIdx.x;
  for (int j = t; j < RANGE; j += THREADS) h[j] = 0;
  __syncthreads();

  int beg = (int)((long long)c * E / CHUNKS);
  int end = (int)((long long)(c + 1) * E / CHUNKS);
  int a = min(end, (beg + 3) & ~3);
  for (int i = beg + t; i < a; i += THREADS) {
    unsigned u = (unsigned)(arr[i] - lo);
    if (u < span) atomicAdd(&h[u], 1);
  }
  for (int i4 = a + t * 4; i4 + 3 < end; i4 += THREADS * 4) {
    int4 v = *(const int4*)(arr + i4);
    unsigned u0 = (unsigned)(v.x - lo), u1 = (unsigned)(v.y - lo);
    unsigned u2 = (unsigned)(v.z - lo), u3 = (unsigned)(v.w - lo);
    if (u0 < span) atomicAdd(&h[u0], 1);
    if (u1 < span) atomicAdd(&h[u1], 1);
    if (u2 < span) atomicAdd(&h[u2], 1);
    if (u3 < span) atomicAdd(&h[u3], 1);
  }
  int tail = a + ((end - a) & ~3);
  for (int i = tail + t; i < end; i += THREADS) {
    unsigned u = (unsigned)(arr[i] - lo);
    if (u < span) atomicAdd(&h[u], 1);
  }
  __syncthreads();
  for (int j = t; j < (int)span; j += THREADS) hist[(size_t)c * N + lo + j] = h[j];
}

// ---- reduce hist columns -> invo (from src-hist) ---------------------------
__global__ void k_red_invo(const int* __restrict__ hist, float* __restrict__ inv_out, int N) {
  int v = blockIdx.x * blockDim.x + threadIdx.x;
  if (v >= N) return;
  int s = 0;
#pragma unroll
  for (int c = 0; c < CHUNKS; ++c) s += hist[(size_t)c * N + v];
  inv_out[v] = rsqrtf((float)max(s, 1));
}

// ---- reduce hist columns -> deg_i, invi (from dst-hist) --------------------
__global__ void k_red_degi(const int* __restrict__ hist, int* __restrict__ deg_i,
                           float* __restrict__ inv_in, int N) {
  int v = blockIdx.x * blockDim.x + threadIdx.x;
  if (v >= N) return;
  int s = 0;
#pragma unroll
  for (int c = 0; c < CHUNKS; ++c) s += hist[(size_t)c * N + v];
  deg_i[v] = s;
  inv_in[v] = rsqrtf((float)max(s, 1));
}

// ---- exclusive scan of deg_i -> row_ptr (scan1/scan2 + fused chunkscan) ----
__global__ void k_scan1(const int* __restrict__ deg, int* __restrict__ incl,
                        int* __restrict__ bsums, int N) {
  __shared__ int sd[1024];
  int base = blockIdx.x * 1024;
  for (int j = threadIdx.x; j < 1024; j += THREADS) sd[j] = (base + j < N) ? deg[base + j] : 0;
  __syncthreads();
  for (int off = 1; off < 1024; off <<= 1) {
    int v[4];
#pragma unroll
    for (int k = 0; k < 4; ++k) { int j = threadIdx.x + k * THREADS; v[k] = (j >= off) ? sd[j - off] : 0; }
    __syncthreads();
#pragma unroll
    for (int k = 0; k < 4; ++k) { int j = threadIdx.x + k * THREADS; sd[j] += v[k]; }
    __syncthreads();
  }
  for (int j = threadIdx.x; j < 1024; j += THREADS) if (base + j < N) incl[base + j] = sd[j];
  if (threadIdx.x == 0) bsums[blockIdx.x] = sd[1023];
}

__global__ void k_scan2(const int* __restrict__ bsums, int* __restrict__ boffs, int nb) {
  __shared__ int sd[256];
  int t = threadIdx.x;
  sd[t] = (t < nb) ? bsums[t] : 0;
  __syncthreads();
  for (int off = 1; off < 256; off <<= 1) {
    int v = (t >= off) ? sd[t - off] : 0;
    __syncthreads();
    sd[t] += v;
    __syncthreads();
  }
  if (t < nb) boffs[t] = (t == 0) ? 0 : sd[t - 1];
}

// fused scan3+chunkscan: finalize row_ptr (exclusive) AND convert hist[c][v]
// into per-(chunk,node) scatter offsets in one pass.
__global__ void k_chunkscan(int* __restrict__ hist, int* __restrict__ incl_rowptr,
                            const int* __restrict__ deg, const int* __restrict__ boffs,
                            int N, int E) {
  int v = blockIdx.x * blockDim.x + threadIdx.x;
  if (v == 0) incl_rowptr[N] = E;
  if (v >= N) return;
  int excl = incl_rowptr[v] - deg[v] + boffs[v >> 10];
  incl_rowptr[v] = excl;
  int run = excl;
#pragma unroll
  for (int c = 0; c < CHUNKS; ++c) {
    size_t idx = (size_t)c * N + v;
    int t = hist[idx];
    hist[idx] = run;
    run += t;
  }
}

// ---- CSR fill: rank via LDS atomic on range slice of offsets ---------------
__global__ __launch_bounds__(THREADS)
void k_csr(const int* __restrict__ dst, const int* __restrict__ src,
           const int* __restrict__ offs, int* __restrict__ csr_src,
           int N, int E, int ranges) {
  __shared__ int offL[RANGE];
  int r = blockIdx.x % ranges;
  int c = blockIdx.x / ranges;
  int lo = r * RANGE;
  unsigned span = (unsigned)min(RANGE, N - lo);
  int t = threadIdx.x;
  for (int j = t; j < (int)span; j += THREADS) offL[j] = offs[(size_t)c * N + lo + j];
  __syncthreads();

  int beg = (int)((long long)c * E / CHUNKS);
  int end = (int)((long long)(c + 1) * E / CHUNKS);
  int a = min(end, (beg + 3) & ~3);
  for (int i = beg + t; i < a; i += THREADS) {
    unsigned u = (unsigned)(dst[i] - lo);
    if (u < span) csr_src[atomicAdd(&offL[u], 1)] = src[i];
  }
  for (int i4 = a + t * 4; i4 + 3 < end; i4 += THREADS * 4) {
    int4 d = *(const int4*)(dst + i4);
    int4 s = *(const int4*)(src + i4);
    unsigned u0 = (unsigned)(d.x - lo), u1 = (unsigned)(d.y - lo);
    unsigned u2 = (unsigned)(d.z - lo), u3 = (unsigned)(d.w - lo);
    if (u0 < span) csr_src[atomicAdd(&offL[u0], 1)] = s.x;
    if (u1 < span) csr_src[atomicAdd(&offL[u1], 1)] = s.y;
    if (u2 < span) csr_src[atomicAdd(&offL[u2], 1)] = s.z;
    if (u3 < span) csr_src[atomicAdd(&offL[u3], 1)] = s.w;
  }
  int tail = a + ((end - a) & ~3);
  for (int i = tail + t; i < end; i += THREADS) {
    unsigned u = (unsigned)(dst[i] - lo);
    if (u < span) csr_src[atomicAdd(&offL[u], 1)] = src[i];
  }
}

// ---- cast+scale: XS[v] = fp16(x[v] * invout[v]) ----------------------------
__global__ __launch_bounds__(THREADS)
void k_cast_scale(const float4* __restrict__ X, const float* __restrict__ invo,
                  h8* __restrict__ XS, int N) {
  int i = blockIdx.x * blockDim.x + threadIdx.x;   // one h8 (8 floats) each
  if (i >= N * 16) return;
  int row = i >> 4;
  float s = invo[row];
  float4 a = X[(size_t)i * 2];
  float4 b = X[(size_t)i * 2 + 1];
  h8 h;
  h[0] = (_Float16)(a.x * s); h[1] = (_Float16)(a.y * s);
  h[2] = (_Float16)(a.z * s); h[3] = (_Float16)(a.w * s);
  h[4] = (_Float16)(b.x * s); h[5] = (_Float16)(b.y * s);
  h[6] = (_Float16)(b.z * s); h[7] = (_Float16)(b.w * s);
  XS[i] = h;
}

// ---- fp16 CSR aggregation: O[v] = fp16( sum_{e:dst=v} H[src] (*invo[src]) )
// SCALE=false: table pre-scaled. SCALE=true: multiply invo[src] on the fly
// (invo = 400KB -> L2-resident per XCD; adds ~no cache lines).
template <bool SCALE>
__global__ __launch_bounds__(THREADS)
void k_agg_h(const h8* __restrict__ H, const float* __restrict__ invo,
             const int* __restrict__ row_ptr, const int* __restrict__ csr_src,
             h8* __restrict__ O, int N) {
  int g = blockIdx.x * (THREADS / 16) + (threadIdx.x >> 4);
  int lane = threadIdx.x & 15;
  if (g >= N) return;
  int e = row_ptr[g], end = row_ptr[g + 1];
  float sa[8] = {0.f, 0.f, 0.f, 0.f, 0.f, 0.f, 0.f, 0.f};
  float sb[8] = {0.f, 0.f, 0.f, 0.f, 0.f, 0.f, 0.f, 0.f};
  for (; e + 1 < end; e += 2) {
    int n0 = csr_src[e], n1 = csr_src[e + 1];
    h8 v0 = H[(size_t)n0 * 16 + lane];
    h8 v1 = H[(size_t)n1 * 16 + lane];
    if (SCALE) {
      float w0 = invo[n0], w1 = invo[n1];
#pragma unroll
      for (int j = 0; j < 8; ++j) { sa[j] += (float)v0[j] * w0; sb[j] += (float)v1[j] * w1; }
    } else {
#pragma unroll
      for (int j = 0; j < 8; ++j) { sa[j] += (float)v0[j]; sb[j] += (float)v1[j]; }
    }
  }
  if (e < end) {
    int n0 = csr_src[e];
    h8 v0 = H[(size_t)n0 * 16 + lane];
    float w0 = SCALE ? invo[n0] : 1.f;
#pragma unroll
    for (int j = 0; j < 8; ++j) sa[j] += SCALE ? (float)v0[j] * w0 : (float)v0[j];
  }
  h8 hv;
#pragma unroll
  for (int j = 0; j < 8; ++j) hv[j] = (_Float16)(sa[j] + sb[j]);
  __builtin_nontemporal_store(hv, &O[(size_t)g * 16 + lane]);
}

// ---- fp16 z-gather (+bout): out[v] = sum z[src] + bout (f32 out) -----------
__global__ __launch_bounds__(THREADS)
void k_agg_z(const h8* __restrict__ Z, const int* __restrict__ row_ptr,
             const int* __restrict__ csr_src, const float* __restrict__ bo,
             float4* __restrict__ Out, int N) {
  int g = blockIdx.x * (THREADS / 8) + (threadIdx.x >> 3);
  int lane = threadIdx.x & 7;
  if (g >= N) return;
  int e = row_ptr[g], end = row_ptr[g + 1];
  float sa[8], sb[8] = {0.f, 0.f, 0.f, 0.f, 0.f, 0.f, 0.f, 0.f};
  {
    float4 b0 = ((const float4*)bo)[lane * 2];
    float4 b1 = ((const float4*)bo)[lane * 2 + 1];
    sa[0] = b0.x; sa[1] = b0.y; sa[2] = b0.z; sa[3] = b0.w;
    sa[4] = b1.x; sa[5] = b1.y; sa[6] = b1.z; sa[7] = b1.w;
  }
  for (; e + 1 < end; e += 2) {
    int n0 = csr_src[e], n1 = csr_src[e + 1];
    h8 v0 = Z[(size_t)n0 * 8 + lane];
    h8 v1 = Z[(size_t)n1 * 8 + lane];
#pragma unroll
    for (int j = 0; j < 8; ++j) { sa[j] += (float)v0[j]; sb[j] += (float)v1[j]; }
  }
  if (e < end) {
    h8 v0 = Z[(size_t)csr_src[e] * 8 + lane];
#pragma unroll
    for (int j = 0; j < 8; ++j) sa[j] += (float)v0[j];
  }
  float4 o0 = make_float4(sa[0] + sb[0], sa[1] + sb[1], sa[2] + sb[2], sa[3] + sb[3]);
  float4 o1 = make_float4(sa[4] + sb[4], sa[5] + sb[5], sa[6] + sb[6], sa[7] + sb[7]);
  nt_store_f4(o0, &Out[(size_t)g * 16 + lane * 2]);
  nt_store_f4(o1, &Out[(size_t)g * 16 + lane * 2 + 1]);
}

// ---- MFMA GEMM (layer): Hh = fp16(relu((A@W)*invi + b)) --------------------
__global__ __launch_bounds__(THREADS, 2)
void k_gemm_mfma(const h8* __restrict__ Ah, const float* __restrict__ W,
                 const float* __restrict__ bias, const float* __restrict__ invi,
                 _Float16* __restrict__ Hh, int N) {
  __shared__ _Float16 As[128 * 136];   // [row][k], 272B row stride (17x16B)
  __shared__ _Float16 Ws[128 * 136];   // [col][k] (transposed)
  int t = threadIdx.x;
  int row0 = blockIdx.x * 128;

  {  // stage A: thread -> half-row (64 halfs = 8 x h8)
    int r = t >> 1, hf = t & 1;
    int gr = row0 + r;
    const h8* Arow = Ah + (size_t)gr * 16 + hf * 8;
    h8 z8 = {};
#pragma unroll
    for (int q = 0; q < 8; ++q) {
      h8 v = (gr < N) ? Arow[q] : z8;
      *(h8*)&As[r * 136 + hf * 64 + q * 8] = v;
    }
  }
  {  // stage W transposed, f32 -> fp16
    const float4* Wv = (const float4*)W;
    int n4 = t & 31, kb = t >> 5;
#pragma unroll
    for (int p = 0; p < 16; ++p) {
      int k = kb + p * 8;
      float4 w = Wv[(size_t)k * 32 + n4];
      Ws[(n4 * 4 + 0) * 136 + k] = (_Float16)w.x;
      Ws[(n4 * 4 + 1) * 136 + k] = (_Float16)w.y;
      Ws[(n4 * 4 + 2) * 136 + k] = (_Float16)w.z;
      Ws[(n4 * 4 + 3) * 136 + k] = (_Float16)w.w;
    }
  }
  __syncthreads();

  int wave = t >> 6, lane = t & 63;
  int l15 = lane & 15, lhi = lane >> 4;
  int wr0 = wave * 32;

  h8 a[2][4];
#pragma unroll
  for (int rt = 0; rt < 2; ++rt)
#pragma unroll
    for (int kk = 0; kk < 4; ++kk)
      a[rt][kk] = *(const h8*)&As[(wr0 + rt * 16 + l15) * 136 + kk * 32 + lhi * 8];

  f32x4 acc[2][8] = {};
#pragma unroll
  for (int ct = 0; ct < 8; ++ct) {
    h8 b[4];
#pragma unroll
    for (int kk = 0; kk < 4; ++kk)
      b[kk] = *(const h8*)&Ws[(ct * 16 + l15) * 136 + kk * 32 + lhi * 8];
#pragma unroll
    for (int kk = 0; kk < 4; ++kk) {
      acc[0][ct] = __builtin_amdgcn_mfma_f32_16x16x32_f16(a[0][kk], b[kk], acc[0][ct], 0, 0, 0);
      acc[1][ct] = __builtin_amdgcn_mfma_f32_16x16x32_f16(a[1][kk], b[kk], acc[1][ct], 0, 0, 0);
    }
  }

  float bn[8];
#pragma unroll
  for (int ct = 0; ct < 8; ++ct) bn[ct] = bias[ct * 16 + l15];
#pragma unroll
  for (int rt = 0; rt < 2; ++rt) {
#pragma unroll
    for (int reg = 0; reg < 4; ++reg) {
      int m = row0 + wr0 + rt * 16 + lhi * 4 + reg;
      if (m < N) {
        float si = invi[m];
#pragma unroll
        for (int ct = 0; ct < 8; ++ct) {
          int n = ct * 16 + l15;
          float o = fmaxf(acc[rt][ct][reg] * si + bn[ct], 0.f);
          Hh[(size_t)m * 128 + n] = (_Float16)o;
        }
      }
    }
  }
}

// ---- MFMA z GEMM: Z = fp16(H1@Wo[0:128] + H2@Wo[128:256]) (N x 64) ---------
__global__ __launch_bounds__(THREADS, 2)
void k_gemm_z(const h8* __restrict__ H1, const h8* __restrict__ H2,
              const float* __restrict__ Wo, _Float16* __restrict__ Z, int N) {
  __shared__ _Float16 As[128 * 136];   // [row][k]
  __shared__ _Float16 Ws[64 * 136];    // [col][k]
  int t = threadIdx.x;
  int row0 = blockIdx.x * 128;
  int wave = t >> 6, lane = t & 63;
  int l15 = lane & 15, lhi = lane >> 4;
  int wr0 = wave * 32;

  f32x4 acc[2][4] = {};
#pragma unroll 1
  for (int hf = 0; hf < 2; ++hf) {
    if (hf) __syncthreads();           // all reads of As/Ws done
    {
      int r = t >> 1, rh = t & 1;
      int gr = row0 + r;
      const h8* Asrc = (hf ? H2 : H1) + (size_t)gr * 16 + rh * 8;
      h8 z8 = {};
#pragma unroll
      for (int q = 0; q < 8; ++q) {
        h8 v = (gr < N) ? Asrc[q] : z8;
        *(h8*)&As[r * 136 + rh * 64 + q * 8] = v;
      }
    }
    {
      const float4* Wv = (const float4*)Wo;
      int n4 = t & 15, kb = t >> 4;
#pragma unroll
      for (int p = 0; p < 8; ++p) {
        int k = kb + p * 16;
        float4 w = Wv[(size_t)(hf * 128 + k) * 16 + n4];
        Ws[(n4 * 4 + 0) * 136 + k] = (_Float16)w.x;
        Ws[(n4 * 4 + 1) * 136 + k] = (_Float16)w.y;
        Ws[(n4 * 4 + 2) * 136 + k] = (_Float16)w.z;
        Ws[(n4 * 4 + 3) * 136 + k] = (_Float16)w.w;
      }
    }
    __syncthreads();

    h8 a[2][4];
#pragma unroll
    for (int rt = 0; rt < 2; ++rt)
#pragma unroll
      for (int kk = 0; kk < 4; ++kk)
        a[rt][kk] = *(const h8*)&As[(wr0 + rt * 16 + l15) * 136 + kk * 32 + lhi * 8];
#pragma unroll
    for (int ct = 0; ct < 4; ++ct) {
      h8 b[4];
#pragma unroll
      for (int kk = 0; kk < 4; ++kk)
        b[kk] = *(const h8*)&Ws[(ct * 16 + l15) * 136 + kk * 32 + lhi * 8];
#pragma unroll
      for (int kk = 0; kk < 4; ++kk) {
        acc[0][ct] = __builtin_amdgcn_mfma_f32_16x16x32_f16(a[0][kk], b[kk], acc[0][ct], 0, 0, 0);
        acc[1][ct] = __builtin_amdgcn_mfma_f32_16x16x32_f16(a[1][kk], b[kk], acc[1][ct], 0, 0, 0);
      }
    }
  }

#pragma unroll
  for (int rt = 0; rt < 2; ++rt) {
#pragma unroll
    for (int reg = 0; reg < 4; ++reg) {
      int m = row0 + wr0 + rt * 16 + lhi * 4 + reg;
      if (m < N) {
#pragma unroll
        for (int ct = 0; ct < 4; ++ct) {
          int n = ct * 16 + l15;
          Z[(size_t)m * 64 + n] = (_Float16)acc[rt][ct][reg];
        }
      }
    }
  }
}

// ---------------------------------------------------------------------------
extern "C" void kernel_launch(void* const* d_in, const int* in_sizes, int n_in,
                              void* d_out, int out_size, void* d_ws, size_t ws_size,
                              hipStream_t stream) {
  const float* x    = (const float*)d_in[0];
  const int*   src  = (const int*)d_in[1];
  const int*   dst  = (const int*)d_in[2];
  const float* W1   = (const float*)d_in[3];
  const float* b1   = (const float*)d_in[4];
  const float* W2   = (const float*)d_in[5];
  const float* b2   = (const float*)d_in[6];
  const float* Wout = (const float*)d_in[7];
  const float* bout = (const float*)d_in[8];
  float* out = (float*)d_out;

  const int IN = 128;
  const int N = in_sizes[0] / IN;   // 100000
  const int E = in_sizes[1];        // 1600000
  const int ranges = (N + RANGE - 1) / RANGE;  // 4

  char* p = (char*)d_ws;
  auto alloc = [&](size_t bytes) -> char* {
    char* r = p;
    p += (bytes + 255) & ~(size_t)255;
    return r;
  };
  int* hist = (int*)alloc((size_t)CHUNKS * N * 4);   // src-hist, then dst-hist/offsets
  h8* bZ = (h8*)alloc((size_t)N * 64 * 2);   // z (fp16, N x 64)
  h8* bX = (h8*)alloc((size_t)N * 128 * 2);  // xs, then aggB
  h8* bA = (h8*)alloc((size_t)N * 128 * 2);  // aggA, then h2h
  h8* bH = (h8*)alloc((size_t)N * 128 * 2);  // h1h
  float* invo   = (float*)alloc((size_t)N * 4);
  float* invi   = (float*)alloc((size_t)N * 4);
  int* deg_i    = (int*)alloc((size_t)N * 4);
  int* row_ptr  = (int*)alloc((size_t)(N + 1) * 4);
  int* bsums    = (int*)alloc(1024);
  int* boffs    = (int*)alloc(1024);
  int* csr_src  = (int*)alloc((size_t)E * 4);

  const int nThread = (N + THREADS - 1) / THREADS;

  // ---- CSR build: no global atomics, one hist buffer reused ----------------
  k_hist<<<ranges * CHUNKS, THREADS, 0, stream>>>(src, hist, N, E, ranges);
  k_red_invo<<<nThread, THREADS, 0, stream>>>(hist, invo, N);
  k_hist<<<ranges * CHUNKS, THREADS, 0, stream>>>(dst, hist, N, E, ranges);
  k_red_degi<<<nThread, THREADS, 0, stream>>>(hist, deg_i, invi, N);
  int nb1 = (N + 1023) / 1024;
  k_scan1<<<nb1, THREADS, 0, stream>>>(deg_i, row_ptr, bsums, N);
  k_scan2<<<1, 256, 0, stream>>>(bsums, boffs, nb1);
  k_chunkscan<<<nThread, THREADS, 0, stream>>>(hist, row_ptr, deg_i, boffs, N, E);
  k_csr<<<ranges * CHUNKS, THREADS, 0, stream>>>(dst, src, hist, csr_src, N, E, ranges);

  const int aggGrid  = (N + (THREADS / 16) - 1) / (THREADS / 16);
  const int aggzGrid = (N + (THREADS / 8) - 1) / (THREADS / 8);
  const int gemmGrid = (N + 127) / 128;
  const int castGrid = (N * 16 + THREADS - 1) / THREADS;

  // ---- layer 1 -------------------------------------------------------------
  k_cast_scale<<<castGrid, THREADS, 0, stream>>>((const float4*)x, invo, bX, N);
  k_agg_h<false><<<aggGrid, THREADS, 0, stream>>>(bX, nullptr, row_ptr, csr_src, bA, N); // aggA
  k_gemm_mfma<<<gemmGrid, THREADS, 0, stream>>>(bA, W1, b1, invi, (_Float16*)bH, N);     // h1h

  // ---- layer 2 (gather scales h1 by invo[src] on the fly) ------------------
  k_agg_h<true><<<aggGrid, THREADS, 0, stream>>>(bH, invo, row_ptr, csr_src, bX, N);     // aggB
  k_gemm_mfma<<<gemmGrid, THREADS, 0, stream>>>(bX, W2, b2, invi, (_Float16*)bA, N);     // h2h

  // ---- z = fp16(h1h@Wo1 + h2h@Wo2) then out = A@z + bout -------------------
  k_gemm_z<<<gemmGrid, THREADS, 0, stream>>>(bH, bA, Wout, (_Float16*)bZ, N);
  k_agg_z<<<aggzGrid, THREADS, 0, stream>>>(bZ, row_ptr, csr_src, bout, (float4*)out, N);
}